// Round 1
// 177.269 us; speedup vs baseline: 1.0880x; 1.0880x over previous
//
#include <hip/hip_runtime.h>

// Round 7: gemm_all restructured.
//  (1) 2-phase double-buffered K-loop (T3-min): stage kt+1 into buf^1 before
//      computing buf[cur]; ONE barrier per kt (was 2). Load latency hides
//      under MFMA + the other buffer's staging.
//  (2) LDS XOR swizzle (T2), both-sides: gld16 dest stays linear, global
//      source k-chunk pre-swizzled with (lane&3)^((lane>>3)&3); ds_read side
//      applies lq^((lr>>1)&3). Kills the 8-way bank conflict (2.88M cyc).
//  (3) Bijective XCD-chunked block swizzle (T1): the 8 n-tile blocks sharing
//      an A-tile (rel&7) land on ONE XCD, temporally adjacent; groups
//      interleaved across d5/d3/d1 per XCD for balance. 1152 = 8*144.
//  prep (L1) unchanged from R6.

#define BATCH 4096
#define DTOT 4608
#define NMUL 512

typedef __attribute__((ext_vector_type(8))) short short8;
typedef __attribute__((ext_vector_type(8))) unsigned short ushort8;
typedef __attribute__((ext_vector_type(4))) float float4v;

#define XPL_BYTES (9ull * BATCH * NMUL * 2)

__device__ __forceinline__ unsigned short f2bf(float f) {
    unsigned int u = __builtin_bit_cast(unsigned int, f);
    return (unsigned short)((u + 0x7fffu + ((u >> 16) & 1u)) >> 16);
}
__device__ __forceinline__ void gld16(const unsigned short* g, unsigned short* l) {
    __builtin_amdgcn_global_load_lds(
        (const __attribute__((address_space(1))) unsigned int*)(const void*)g,
        (__attribute__((address_space(3))) unsigned int*)(void*)l, 16, 0, 0);
}
__device__ __forceinline__ void colmap(int col, int& c, int& u) {
    if (col < 512)       { c = 0; u = col; }
    else if (col < 2048) { int t = col - 512;  c = 1 + t % 3; u = t / 3; }
    else                 { int t = col - 2048; c = 4 + t % 5; u = t / 5; }
}

// ---- L1: prep (deint rows + W convert tiles) — unchanged ----
__global__ __launch_bounds__(256) void prep(const float* __restrict__ x,
                                            const float* __restrict__ w0,
                                            const float* __restrict__ w1,
                                            const float* __restrict__ w2,
                                            unsigned short* __restrict__ Xp,
                                            unsigned short* __restrict__ Wt) {
    __shared__ unsigned short buf[4608];
    const int tid = threadIdx.x;
    const int b = blockIdx.x;
    if (b < BATCH) {
        const int row = b;
        const float4v* src = (const float4v*)(x + (size_t)row * DTOT);
        for (int p = tid; p < DTOT / 4; p += 256) {
            float4v v = src[p];
#pragma unroll
            for (int j = 0; j < 4; ++j) {
                int c, u; colmap(p * 4 + j, c, u);
                buf[c * NMUL + u] = f2bf(v[j]);
            }
        }
        __syncthreads();
        for (int q = tid; q < DTOT / 8; q += 256) {
            const int c = q >> 6, u8 = q & 63;
            *(ushort8*)(Xp + ((size_t)(c * BATCH + row) * NMUL) + u8 * 8) =
                *(const ushort8*)&buf[c * NMUL + u8 * 8];
        }
    } else {
        const int t = b - BATCH;              // 0..191
        const int ch = t >> 6, tt = t & 63;
        const int tk = (tt >> 3) * 64, tn = (tt & 7) * 64;
        const float* W = (ch == 0) ? w0 : (ch == 1) ? w1 : w2;
        const int r0 = tid >> 4, c4 = (tid & 15) * 4;
#pragma unroll
        for (int rr = 0; rr < 4; ++rr) {
            const int row = r0 + rr * 16;     // k within tile
            float4v v = *(const float4v*)(W + (size_t)(tk + row) * NMUL + tn + c4);
#pragma unroll
            for (int j = 0; j < 4; ++j) buf[(c4 + j) * 72 + row] = f2bf(v[j]);
        }
        __syncthreads();
        for (int q = tid; q < 512; q += 256) {
            const int nn = q >> 3, k8 = q & 7;
            *(ushort8*)(Wt + ((size_t)(ch * NMUL + tn + nn) * NMUL) + tk + k8 * 8) =
                *(const ushort8*)&buf[nn * 72 + k8 * 8];
        }
    }
}

// ---- d in {3,5}: 64 rows x 64 cols x D planes, wave = plane, dbuf K-loop ----
template <int D, int PBASE, int XOFF, int WCH>
__device__ __forceinline__ void body_d35(int rel,
                                         const unsigned short* __restrict__ Xp,
                                         const unsigned short* __restrict__ Wt,
                                         float* __restrict__ out,
                                         unsigned short (*As)[10240],
                                         unsigned short (*Bs)[2048]) {
    const int tid = threadIdx.x;
    const int lane = tid & 63;
    const int w = tid >> 6;                   // 0..4; planes use 0..D-1
    const int lr = lane & 15;
    const int lq = lane >> 4;

    const int n0 = (rel & 7) * 64;
    const int m0 = (rel >> 3) * 64;

    // T2: global source pre-swizzled k-chunk; same involution on read side.
    const int ksw = ((lane & 3) ^ ((lane >> 3) & 3)) * 8;
    const int rsw = (lq ^ ((lr >> 1) & 3)) * 8;

    const unsigned short* Ag =
        Xp + ((size_t)(PBASE + w) * BATCH + m0 + (lane >> 2)) * NMUL + ksw;
    const unsigned short* Bg =
        Wt + ((size_t)WCH * NMUL + n0 + (lane >> 2)) * NMUL + ksw;

    float4v acc[4][4];
#pragma unroll
    for (int a = 0; a < 4; ++a)
#pragma unroll
        for (int b = 0; b < 4; ++b) acc[a][b] = (float4v)0.f;

    // prologue: stage kt=0 into buffer 0
    if (w < D) {
#pragma unroll
        for (int p = 0; p < 4; ++p)
            gld16(Ag + (size_t)p * 16 * NMUL, As[0] + w * 2048 + p * 512);
    }
    if (w < 4) gld16(Bg + (size_t)w * 16 * NMUL, Bs[0] + w * 512);
    __syncthreads();

    for (int kt = 0; kt < 16; ++kt) {
        const int cur = kt & 1;
        if (kt < 15) {
            const int ko = (kt + 1) * 32;
            if (w < D) {
#pragma unroll
                for (int p = 0; p < 4; ++p)
                    gld16(Ag + (size_t)p * 16 * NMUL + ko,
                          As[cur ^ 1] + w * 2048 + p * 512);
            }
            if (w < 4)
                gld16(Bg + (size_t)w * 16 * NMUL + ko, Bs[cur ^ 1] + w * 512);
        }
        if (w < D) {
            const unsigned short* Al = As[cur] + w * 2048;
            const unsigned short* Bl = Bs[cur];
            short8 af[4], bf[4];
#pragma unroll
            for (int mi = 0; mi < 4; ++mi)
                af[mi] = *(const short8*)(Al + (mi * 16 + lr) * 32 + rsw);
#pragma unroll
            for (int ni = 0; ni < 4; ++ni)
                bf[ni] = *(const short8*)(Bl + (ni * 16 + lr) * 32 + rsw);
#pragma unroll
            for (int mi = 0; mi < 4; ++mi)
#pragma unroll
                for (int ni = 0; ni < 4; ++ni)
                    acc[mi][ni] = __builtin_amdgcn_mfma_f32_16x16x32_bf16(
                        af[mi], bf[ni], acc[mi][ni], 0, 0, 0);
        }
        __syncthreads();
    }

    // epilogue: LDS-interleave (verified R5/R6), Cs reuses the As region
    float* Cs = (float*)As;
    const float PW = 0.044194173824159216f;
#pragma unroll
    for (int mc = 0; mc < 4; ++mc) {
        if (w < D) {
#pragma unroll
            for (int ni = 0; ni < 4; ++ni)
#pragma unroll
                for (int r = 0; r < 4; ++r)
                    Cs[(lq * 4 + r) * (64 * D) + (ni * 16 + lr) * D + w] =
                        acc[mc][ni][r] * PW;
        }
        __syncthreads();
        constexpr int F4 = 16 * 16 * D;
        for (int f = tid; f < F4; f += 320) {
            const int row = f / (16 * D);
            const int c4  = f % (16 * D);
            *(float4v*)(out + (size_t)(m0 + mc * 16 + row) * DTOT + XOFF + n0 * D + c4 * 4) =
                *(const float4v*)(Cs + f * 4);
        }
        __syncthreads();
    }
}

// ---- d=1: 128x128, waves 0..3 (wave 4 barriers only), dbuf K-loop ----
// A and B both packed into As[buf]: A at 0 (8 KiB), B at ushort 4096 (8 KiB).
__device__ __forceinline__ void body_d1(int rel,
                                        const unsigned short* __restrict__ Xp,
                                        const unsigned short* __restrict__ Wt,
                                        const float* __restrict__ b0,
                                        float* __restrict__ out,
                                        unsigned short (*As)[10240]) {
    const int tid = threadIdx.x;
    const int lane = tid & 63;
    const int w = tid >> 6;
    const int lr = lane & 15;
    const int lq = lane >> 4;
    const int wm = (w >> 1) * 64;
    const int wn = (w & 1) * 64;

    const int n0 = (rel & 3) * 128;
    const int m0 = (rel >> 2) * 128;

    const int ksw = ((lane & 3) ^ ((lane >> 3) & 3)) * 8;
    const int rsw = (lq ^ ((lr >> 1) & 3)) * 8;

    const unsigned short* Ag = Xp + (size_t)(m0 + w * 32 + (lane >> 2)) * NMUL + ksw;
    const unsigned short* Bg = Wt + (size_t)(n0 + w * 32 + (lane >> 2)) * NMUL + ksw;

    float4v acc[4][4];
#pragma unroll
    for (int a = 0; a < 4; ++a)
#pragma unroll
        for (int b = 0; b < 4; ++b) acc[a][b] = (float4v)0.f;

    if (w < 4) {
        gld16(Ag, As[0] + w * 1024);
        gld16(Ag + 16 * NMUL, As[0] + w * 1024 + 512);
        gld16(Bg, As[0] + 4096 + w * 1024);
        gld16(Bg + 16 * NMUL, As[0] + 4096 + w * 1024 + 512);
    }
    __syncthreads();

    for (int kt = 0; kt < 16; ++kt) {
        const int cur = kt & 1;
        if (kt < 15 && w < 4) {
            const int ko = (kt + 1) * 32;
            gld16(Ag + ko, As[cur ^ 1] + w * 1024);
            gld16(Ag + ko + 16 * NMUL, As[cur ^ 1] + w * 1024 + 512);
            gld16(Bg + ko, As[cur ^ 1] + 4096 + w * 1024);
            gld16(Bg + ko + 16 * NMUL, As[cur ^ 1] + 4096 + w * 1024 + 512);
        }
        if (w < 4) {
            const unsigned short* Ab = As[cur];
            const unsigned short* Bb = As[cur] + 4096;
            short8 af[4], bf[4];
#pragma unroll
            for (int mi = 0; mi < 4; ++mi)
                af[mi] = *(const short8*)(Ab + (wm + mi * 16 + lr) * 32 + rsw);
#pragma unroll
            for (int ni = 0; ni < 4; ++ni)
                bf[ni] = *(const short8*)(Bb + (wn + ni * 16 + lr) * 32 + rsw);
#pragma unroll
            for (int mi = 0; mi < 4; ++mi)
#pragma unroll
                for (int ni = 0; ni < 4; ++ni)
                    acc[mi][ni] = __builtin_amdgcn_mfma_f32_16x16x32_bf16(
                        af[mi], bf[ni], acc[mi][ni], 0, 0, 0);
        }
        __syncthreads();
    }

    if (w < 4) {
        const float PW = 0.044194173824159216f;
#pragma unroll
        for (int ni = 0; ni < 4; ++ni) {
            const int col = n0 + wn + ni * 16 + lr;
            const float bias = b0[col];
#pragma unroll
            for (int mi = 0; mi < 4; ++mi)
#pragma unroll
                for (int r = 0; r < 4; ++r)
                    out[(size_t)(m0 + wm + mi * 16 + lq * 4 + r) * DTOT + col] =
                        acc[mi][ni][r] * PW + bias;
        }
    }
}

// ---- L2: all 9 channel-GEMMs in one launch, XCD-chunked block swizzle ----
__global__ __launch_bounds__(320) void gemm_all(const unsigned short* __restrict__ Xp,
                                                const unsigned short* __restrict__ Wt,
                                                const float* __restrict__ b0,
                                                float* __restrict__ out) {
    __shared__ __align__(16) unsigned short As[2][10240];  // 40 KiB (A dbuf / d1 A+B / Cs)
    __shared__ __align__(16) unsigned short Bs[2][2048];   // 8 KiB  (d35 B dbuf)

    // T1: hw blockIdx round-robins XCDs. Map so the 8 blocks sharing an
    // A-tile (work b: 8g..8g+7) are consecutive on ONE XCD, and each XCD's
    // 18 groups interleave d5/d3/d1 (g ≡ xcd mod 8). Bijective: 1152 = 8*144.
    const int hw = blockIdx.x;
    const int xcd = hw & 7, j = hw >> 3;                  // j in [0,144)
    const int b = ((xcd + ((j >> 3) << 3)) << 3) + (j & 7);

    if (b < 512)       body_d35<5, 4, 2048, 2>(b, Xp, Wt, out, As, Bs);
    else if (b < 1024) body_d35<3, 1, 512, 1>(b - 512, Xp, Wt, out, As, Bs);
    else               body_d1(b - 1024, Xp, Wt, b0, out, As);
}

extern "C" void kernel_launch(void* const* d_in, const int* in_sizes, int n_in,
                              void* d_out, int out_size, void* d_ws, size_t ws_size,
                              hipStream_t stream) {
    const float* x  = (const float*)d_in[0];
    const float* w0 = (const float*)d_in[1];
    const float* w1 = (const float*)d_in[2];
    const float* w2 = (const float*)d_in[3];
    const float* b0 = (const float*)d_in[4];
    float* out = (float*)d_out;

    unsigned short* Xp = (unsigned short*)d_ws;
    unsigned short* Wt = (unsigned short*)((char*)d_ws + XPL_BYTES);

    prep<<<dim3(BATCH + 192), dim3(256), 0, stream>>>(x, w0, w1, w2, Xp, Wt);
    gemm_all<<<dim3(1152), dim3(320), 0, stream>>>(Xp, Wt, b0, out);
}